// Round 1
// baseline (847.821 us; speedup 1.0000x reference)
//
#include <hip/hip_runtime.h>
#include <math.h>

// Problem constants
constexpr int N = 10000;
constexpr int E = 160000;
constexpr int B = 16;
// H=64, A=8, IN=16, L=2

__device__ __forceinline__ float silu_f(float x) {
    return x / (1.0f + __expf(-x));
}

// ---------------- K1: embedding h = TP(concat(x,anf), na, W_emb) + b ----------------
__global__ __launch_bounds__(256) void k_embed(
        const float* __restrict__ x, const float* __restrict__ anf,
        const float* __restrict__ na, const float* __restrict__ W,
        const float* __restrict__ b, float* __restrict__ h) {
    int wv = threadIdx.x >> 6;
    int k = threadIdx.x & 63;
    int n = blockIdx.x * 4 + wv;
    float naR[8];
#pragma unroll
    for (int j = 0; j < 8; ++j) naR[j] = na[n * 8 + j];
    float acc = b[k];
#pragma unroll
    for (int i = 0; i < 17; ++i) {
        float xi = (i < 16) ? x[n * 16 + i] : anf[n];
#pragma unroll
        for (int j = 0; j < 8; ++j)
            acc = fmaf(xi * naR[j], W[(i * 8 + j) * 64 + k], acc);
    }
    h[(size_t)n * 64 + k] = acc;
}

// ---------------- K2: per-node P1/P2 precompute for message TP ----------------
// P layout: P[n][part(2)][j(8)][k(64)]  (1024 floats per node)
constexpr int K2_NPB = 16;
__global__ __launch_bounds__(512) void k_precompute(
        const float* __restrict__ h, const float* __restrict__ anf,
        const float* __restrict__ Wm1_l, float* __restrict__ P) {
    __shared__ float ha[K2_NPB][66];
    int n0 = blockIdx.x * K2_NPB;
    for (int idx = threadIdx.x; idx < K2_NPB * 65; idx += 512) {
        int nn = idx / 65, i = idx % 65;
        ha[nn][i] = (i < 64) ? h[(size_t)(n0 + nn) * 64 + i] : anf[n0 + nn];
    }
    __syncthreads();
    int o = threadIdx.x;  // o = j*64+k
    float acc1[K2_NPB], acc2[K2_NPB];
#pragma unroll
    for (int nn = 0; nn < K2_NPB; ++nn) { acc1[nn] = 0.f; acc2[nn] = 0.f; }
    for (int i = 0; i < 65; ++i) {
        float w1 = Wm1_l[i * 512 + o];
        float w2 = Wm1_l[(65 + i) * 512 + o];
#pragma unroll
        for (int nn = 0; nn < K2_NPB; ++nn) {
            float a = ha[nn][i];
            acc1[nn] = fmaf(a, w1, acc1[nn]);
            acc2[nn] = fmaf(a, w2, acc2[nn]);
        }
    }
#pragma unroll
    for (int nn = 0; nn < K2_NPB; ++nn) {
        P[(size_t)(n0 + nn) * 1024 + o] = acc1[nn];
        P[(size_t)(n0 + nn) * 1024 + 512 + o] = acc2[nn];
    }
}

// ---------------- K3: edge kernel: m1 (via P), silu, m2 TP, silu, scatter ----------------
__global__ __launch_bounds__(256) void k_edge(
        const int* __restrict__ eidx, const float* __restrict__ ea,
        const float* __restrict__ amf, const float* __restrict__ P,
        const float* __restrict__ Wm1_l, const float* __restrict__ bm1_l,
        const float* __restrict__ Wm2_l, const float* __restrict__ bm2_l,
        float* __restrict__ agg) {
    __shared__ float m_s[64][64];
    __shared__ __align__(16) float w_l[16 * 512];
    __shared__ float ea_s[64][8];
    __shared__ float w130[512];
    int tid = threadIdx.x;
    int w = tid >> 6, k = tid & 63;
    int e0 = blockIdx.x * 64;
    for (int idx = tid; idx < 512; idx += 256) w130[idx] = Wm1_l[130 * 512 + idx];
    for (int idx = tid; idx < 512; idx += 256) (&ea_s[0][0])[idx] = ea[(size_t)e0 * 8 + idx];
    __syncthreads();
    float bm1k = bm1_l[k];
    // phase 1: m = silu(m1) for this wave's 16 edges
#pragma unroll 2
    for (int q = 0; q < 16; ++q) {
        int le = w * 16 + q;
        int e = e0 + le;
        int src = eidx[e];
        int dst = eidx[E + e];
        float amfe = amf[e];
        const float* P1 = P + (size_t)dst * 1024;
        const float* P2 = P + (size_t)src * 1024 + 512;
        float macc = bm1k;
#pragma unroll
        for (int j = 0; j < 8; ++j) {
            float s = P1[j * 64 + k] + P2[j * 64 + k] + amfe * w130[j * 64 + k];
            macc = fmaf(ea_s[le][j], s, macc);
        }
        m_s[le][k] = silu_f(macc);
    }
    float bm2k = bm2_l[k];
    // phase 2: m2[k] = silu(bm2 + sum_j ea_j * C[j][k]),  C[j][k] = sum_i m_i * Wm2[i][j][k]
    for (int pass = 0; pass < 2; ++pass) {
        float accC[8][8];
#pragma unroll
        for (int e8 = 0; e8 < 8; ++e8)
#pragma unroll
            for (int j = 0; j < 8; ++j) accC[e8][j] = 0.f;
        for (int chunk = 0; chunk < 4; ++chunk) {
            __syncthreads();
            const float4* s4 = (const float4*)(Wm2_l + chunk * 16 * 512);
            float4* d4 = (float4*)w_l;
            for (int t = tid; t < 2048; t += 256) d4[t] = s4[t];
            __syncthreads();
#pragma unroll 4
            for (int ii = 0; ii < 16; ++ii) {
                float tmp[8];
#pragma unroll
                for (int e8 = 0; e8 < 8; ++e8)
                    tmp[e8] = m_s[w * 16 + pass * 8 + e8][chunk * 16 + ii];
#pragma unroll
                for (int j = 0; j < 8; ++j) {
                    float wvv = w_l[ii * 512 + j * 64 + k];
#pragma unroll
                    for (int e8 = 0; e8 < 8; ++e8)
                        accC[e8][j] = fmaf(tmp[e8], wvv, accC[e8][j]);
                }
            }
        }
#pragma unroll
        for (int e8 = 0; e8 < 8; ++e8) {
            int le = w * 16 + pass * 8 + e8;
            int e = e0 + le;
            float val = bm2k;
#pragma unroll
            for (int j = 0; j < 8; ++j) val = fmaf(ea_s[le][j], accC[e8][j], val);
            float m2v = silu_f(val);
            int dst = eidx[E + e];
            atomicAdd(&agg[(size_t)dst * 64 + k], m2v);
        }
    }
}

// ---------------- K4: node update u1=silu(TP(xin,na,Wu1)), u2=TP(u1,na,Wu2), h+=u2 ----------------
constexpr int K4_NPB = 8;
__global__ __launch_bounds__(512) void k_update(
        const float* __restrict__ anf, const float* __restrict__ na,
        const float* __restrict__ agg,
        const float* __restrict__ Wu1_l, const float* __restrict__ bu1_l,
        const float* __restrict__ Wu2_l, const float* __restrict__ bu2_l,
        float* __restrict__ h) {
    __shared__ __align__(16) float xin[K4_NPB][132];
    __shared__ float C[K4_NPB][512];
    __shared__ __align__(16) float u_s[K4_NPB][64];
    __shared__ float na_s[K4_NPB][8];
    int tid = threadIdx.x;
    int n0 = blockIdx.x * K4_NPB;
    for (int idx = tid; idx < K4_NPB * 8; idx += 512) na_s[idx >> 3][idx & 7] = na[(size_t)n0 * 8 + idx];
    for (int idx = tid; idx < K4_NPB * 132; idx += 512) {
        int nn = idx / 132, i = idx % 132;
        int n = n0 + nn;
        float v = 0.f;
        if (i < 64) v = h[(size_t)n * 64 + i];
        else if (i == 64) v = anf[n];
        else if (i < 129) v = agg[(size_t)n * 64 + (i - 65)];
        xin[nn][i] = v;
    }
    __syncthreads();
    int o = tid;
    {
        float acc[K4_NPB];
#pragma unroll
        for (int nn = 0; nn < K4_NPB; ++nn) acc[nn] = 0.f;
        for (int i4 = 0; i4 < 32; ++i4) {
            float w0 = Wu1_l[(i4 * 4 + 0) * 512 + o];
            float w1 = Wu1_l[(i4 * 4 + 1) * 512 + o];
            float w2 = Wu1_l[(i4 * 4 + 2) * 512 + o];
            float w3 = Wu1_l[(i4 * 4 + 3) * 512 + o];
#pragma unroll
            for (int nn = 0; nn < K4_NPB; ++nn) {
                float4 xv = *(const float4*)&xin[nn][i4 * 4];
                acc[nn] = fmaf(xv.x, w0, acc[nn]);
                acc[nn] = fmaf(xv.y, w1, acc[nn]);
                acc[nn] = fmaf(xv.z, w2, acc[nn]);
                acc[nn] = fmaf(xv.w, w3, acc[nn]);
            }
        }
        float w128 = Wu1_l[128 * 512 + o];
#pragma unroll
        for (int nn = 0; nn < K4_NPB; ++nn) {
            acc[nn] = fmaf(xin[nn][128], w128, acc[nn]);
            C[nn][o] = acc[nn];
        }
    }
    __syncthreads();
    {   // u = silu(bu1 + sum_j na*C)
        int nn = tid >> 6, k = tid & 63;
        float v = bu1_l[k];
#pragma unroll
        for (int j = 0; j < 8; ++j) v = fmaf(na_s[nn][j], C[nn][j * 64 + k], v);
        u_s[nn][k] = silu_f(v);
    }
    __syncthreads();
    {
        float acc[K4_NPB];
#pragma unroll
        for (int nn = 0; nn < K4_NPB; ++nn) acc[nn] = 0.f;
        for (int i4 = 0; i4 < 16; ++i4) {
            float w0 = Wu2_l[(i4 * 4 + 0) * 512 + o];
            float w1 = Wu2_l[(i4 * 4 + 1) * 512 + o];
            float w2 = Wu2_l[(i4 * 4 + 2) * 512 + o];
            float w3 = Wu2_l[(i4 * 4 + 3) * 512 + o];
#pragma unroll
            for (int nn = 0; nn < K4_NPB; ++nn) {
                float4 xv = *(const float4*)&u_s[nn][i4 * 4];
                acc[nn] = fmaf(xv.x, w0, acc[nn]);
                acc[nn] = fmaf(xv.y, w1, acc[nn]);
                acc[nn] = fmaf(xv.z, w2, acc[nn]);
                acc[nn] = fmaf(xv.w, w3, acc[nn]);
            }
        }
        __syncthreads();  // C still being read? no: phase B read C before; safe to overwrite after this barrier
#pragma unroll
        for (int nn = 0; nn < K4_NPB; ++nn) C[nn][o] = acc[nn];
    }
    __syncthreads();
    {
        int nn = tid >> 6, k = tid & 63;
        float v = bu2_l[k];
#pragma unroll
        for (int j = 0; j < 8; ++j) v = fmaf(na_s[nn][j], C[nn][j * 64 + k], v);
        h[(size_t)(n0 + nn) * 64 + k] += v;
    }
}

// ---------------- K6: prepool p=silu(TP(h,na,Wp1)); p2=TP(p,na,Wp2); pooled atomics ----------------
__global__ __launch_bounds__(512) void k_prepool(
        const float* __restrict__ h, const float* __restrict__ na,
        const int* __restrict__ batch,
        const float* __restrict__ Wp1, const float* __restrict__ bp1,
        const float* __restrict__ Wp2, const float* __restrict__ bp2,
        float* __restrict__ pooled, float* __restrict__ cnt) {
    __shared__ __align__(16) float xin[K4_NPB][64];
    __shared__ float C[K4_NPB][512];
    __shared__ __align__(16) float u_s[K4_NPB][64];
    __shared__ float na_s[K4_NPB][8];
    int tid = threadIdx.x;
    int n0 = blockIdx.x * K4_NPB;
    for (int idx = tid; idx < K4_NPB * 8; idx += 512) na_s[idx >> 3][idx & 7] = na[(size_t)n0 * 8 + idx];
    for (int idx = tid; idx < K4_NPB * 64; idx += 512) (&xin[0][0])[idx] = h[(size_t)n0 * 64 + idx];
    __syncthreads();
    int o = tid;
    {
        float acc[K4_NPB];
#pragma unroll
        for (int nn = 0; nn < K4_NPB; ++nn) acc[nn] = 0.f;
        for (int i4 = 0; i4 < 16; ++i4) {
            float w0 = Wp1[(i4 * 4 + 0) * 512 + o];
            float w1 = Wp1[(i4 * 4 + 1) * 512 + o];
            float w2 = Wp1[(i4 * 4 + 2) * 512 + o];
            float w3 = Wp1[(i4 * 4 + 3) * 512 + o];
#pragma unroll
            for (int nn = 0; nn < K4_NPB; ++nn) {
                float4 xv = *(const float4*)&xin[nn][i4 * 4];
                acc[nn] = fmaf(xv.x, w0, acc[nn]);
                acc[nn] = fmaf(xv.y, w1, acc[nn]);
                acc[nn] = fmaf(xv.z, w2, acc[nn]);
                acc[nn] = fmaf(xv.w, w3, acc[nn]);
            }
        }
#pragma unroll
        for (int nn = 0; nn < K4_NPB; ++nn) C[nn][o] = acc[nn];
    }
    __syncthreads();
    {
        int nn = tid >> 6, k = tid & 63;
        float v = bp1[k];
#pragma unroll
        for (int j = 0; j < 8; ++j) v = fmaf(na_s[nn][j], C[nn][j * 64 + k], v);
        u_s[nn][k] = silu_f(v);
    }
    __syncthreads();
    {
        float acc[K4_NPB];
#pragma unroll
        for (int nn = 0; nn < K4_NPB; ++nn) acc[nn] = 0.f;
        for (int i4 = 0; i4 < 16; ++i4) {
            float w0 = Wp2[(i4 * 4 + 0) * 512 + o];
            float w1 = Wp2[(i4 * 4 + 1) * 512 + o];
            float w2 = Wp2[(i4 * 4 + 2) * 512 + o];
            float w3 = Wp2[(i4 * 4 + 3) * 512 + o];
#pragma unroll
            for (int nn = 0; nn < K4_NPB; ++nn) {
                float4 xv = *(const float4*)&u_s[nn][i4 * 4];
                acc[nn] = fmaf(xv.x, w0, acc[nn]);
                acc[nn] = fmaf(xv.y, w1, acc[nn]);
                acc[nn] = fmaf(xv.z, w2, acc[nn]);
                acc[nn] = fmaf(xv.w, w3, acc[nn]);
            }
        }
        __syncthreads();
#pragma unroll
        for (int nn = 0; nn < K4_NPB; ++nn) C[nn][o] = acc[nn];
    }
    __syncthreads();
    {
        int nn = tid >> 6, k = tid & 63;
        int n = n0 + nn;
        float v = bp2[k];
#pragma unroll
        for (int j = 0; j < 8; ++j) v = fmaf(na_s[nn][j], C[nn][j * 64 + k], v);
        int bb = batch[n];
        atomicAdd(&pooled[bb * 64 + k], v);
        if (k == 0) atomicAdd(&cnt[bb], 1.0f);
    }
}

// ---------------- K7: mean pool finish + final MLP ----------------
__global__ __launch_bounds__(1024) void k_final(
        const float* __restrict__ pooled, const float* __restrict__ cnt,
        const float* __restrict__ Wq1, const float* __restrict__ bq1,
        const float* __restrict__ Wq2, const float* __restrict__ bq2,
        float* __restrict__ out) {
    __shared__ float g[16][64];
    int b = threadIdx.x >> 6, k = threadIdx.x & 63;
    g[b][k] = pooled[b * 64 + k] / fmaxf(cnt[b], 1.0f);
    __syncthreads();
    float acc = bq1[k];
#pragma unroll
    for (int i = 0; i < 64; ++i) acc = fmaf(g[b][i], Wq1[i * 64 + k], acc);
    float v = silu_f(acc) * Wq2[k];
#pragma unroll
    for (int off = 32; off > 0; off >>= 1) v += __shfl_down(v, off, 64);
    if (k == 0) out[b] = v + bq2[0];
}

extern "C" void kernel_launch(void* const* d_in, const int* in_sizes, int n_in,
                              void* d_out, int out_size, void* d_ws, size_t ws_size,
                              hipStream_t stream) {
    const float* x    = (const float*)d_in[0];
    const int*   eidx = (const int*)  d_in[1];
    const float* ea   = (const float*)d_in[2];
    const float* na   = (const float*)d_in[3];
    const float* amf  = (const float*)d_in[4];
    const float* anf  = (const float*)d_in[5];
    const int*   batch= (const int*)  d_in[6];
    const float* W_emb= (const float*)d_in[7];
    const float* b_emb= (const float*)d_in[8];
    const float* Wm1  = (const float*)d_in[9];
    const float* bm1  = (const float*)d_in[10];
    const float* Wm2  = (const float*)d_in[11];
    const float* bm2  = (const float*)d_in[12];
    const float* Wu1  = (const float*)d_in[13];
    const float* bu1  = (const float*)d_in[14];
    const float* Wu2  = (const float*)d_in[15];
    const float* bu2  = (const float*)d_in[16];
    const float* Wp1  = (const float*)d_in[17];
    const float* bp1  = (const float*)d_in[18];
    const float* Wp2  = (const float*)d_in[19];
    const float* bp2  = (const float*)d_in[20];
    const float* Wq1  = (const float*)d_in[21];
    const float* bq1  = (const float*)d_in[22];
    const float* Wq2  = (const float*)d_in[23];
    const float* bq2  = (const float*)d_in[24];

    float* ws = (float*)d_ws;
    float* h      = ws;                    // N*64
    float* P      = h + (size_t)N * 64;    // N*1024
    float* agg    = P + (size_t)N * 1024;  // N*64
    float* pooled = agg + (size_t)N * 64;  // B*64
    float* cnt    = pooled + B * 64;       // B

    k_embed<<<N / 4, 256, 0, stream>>>(x, anf, na, W_emb, b_emb, h);
    for (int l = 0; l < 2; ++l) {
        hipMemsetAsync(agg, 0, (size_t)N * 64 * sizeof(float), stream);
        k_precompute<<<N / K2_NPB, 512, 0, stream>>>(h, anf, Wm1 + (size_t)l * 131 * 512, P);
        k_edge<<<E / 64, 256, 0, stream>>>(eidx, ea, amf, P,
                                           Wm1 + (size_t)l * 131 * 512, bm1 + l * 64,
                                           Wm2 + (size_t)l * 64 * 512, bm2 + l * 64, agg);
        k_update<<<N / K4_NPB, 512, 0, stream>>>(anf, na, agg,
                                                 Wu1 + (size_t)l * 129 * 512, bu1 + l * 64,
                                                 Wu2 + (size_t)l * 64 * 512, bu2 + l * 64, h);
    }
    hipMemsetAsync(pooled, 0, (size_t)(B * 64 + B) * sizeof(float), stream);
    k_prepool<<<N / K4_NPB, 512, 0, stream>>>(h, na, batch, Wp1, bp1, Wp2, bp2, pooled, cnt);
    k_final<<<1, 1024, 0, stream>>>(pooled, cnt, Wq1, bq1, Wq2, bq2, (float*)d_out);
}